// Round 9
// baseline (132.864 us; speedup 1.0000x reference)
//
#include <hip/hip_runtime.h>

// FDLT: out[b,m,o] = sum_i psiHat[b,m,i] * E[m][i][o]
//   E[m] = cm * X_parity(m) @ D[m]^T   (X = XFc even m, XFs odd m)
// BATCH=2048, B=128 (m), N=256 (i), O=128 (o)
//
// Kernel 1: e_kernel -> Bpack[m][t][cf][lane]·16B (MFMA fragment-packed ->
//   main-kernel B-loads are wave-uniform base + lane*16: dense 1KB bursts).
// Kernel 2 (r9): r8's row-burst glds staging, but 32-row blocks (32 KB LDS)
//   with o split across wave pairs -> 5 blocks/CU. The r8 phase-sum analysis
//   (stage 40 + B 25 + mfma 19 + stores 20 ~= 110us measured) says the limit
//   is PHASE SERIALIZATION at 2 blocks/CU, not any single BW boundary; 5
//   independently-phased blocks/CU lets stage/compute/store overlap.

typedef __attribute__((ext_vector_type(8))) short short8;
typedef __attribute__((ext_vector_type(4))) float f32x4;

#define NBATCH 2048
#define NM 128
#define NI 256   // K dim (i / j)
#define NO 128   // output o dim
// Bpack per m: 8 t-steps x 8 cf x 64 lanes x 8 bf16 = 32768 shorts (64 KB)
#define BPACK_M 32768

#define GLB(p) ((const __attribute__((address_space(1))) void*)(p))
#define LDS(p) ((__attribute__((address_space(3))) void*)(p))

__device__ __forceinline__ unsigned short f2bf(float f) {
  // round-to-nearest-even fp32 -> bf16
  unsigned int u = __builtin_bit_cast(unsigned int, f);
  u += 0x7FFFu + ((u >> 16) & 1u);
  return (unsigned short)(u >> 16);
}

__device__ __forceinline__ short8 cvt8(float4 a, float4 b, float s) {
  short8 v;
  v[0] = (short)f2bf(s * a.x); v[1] = (short)f2bf(s * a.y);
  v[2] = (short)f2bf(s * a.z); v[3] = (short)f2bf(s * a.w);
  v[4] = (short)f2bf(s * b.x); v[5] = (short)f2bf(s * b.y);
  v[6] = (short)f2bf(s * b.z); v[7] = (short)f2bf(s * b.w);
  return v;
}

// ---------------- Kernel 1: E precompute -> fragment-packed Bpack ----------
__global__ __launch_bounds__(256) void e_kernel(
    const float* __restrict__ XFc, const float* __restrict__ XFs,
    const float* __restrict__ D, const float* __restrict__ cmp,
    unsigned short* __restrict__ Bpack)
{
  const int m = blockIdx.x >> 1;
  const int ihalf = blockIdx.x & 1;
  const int tid = threadIdx.x;
  const int lane = tid & 63;
  const int w = tid >> 6;
  const int lr = lane & 15;   // frag row (A) / col (B)
  const int lg = lane >> 4;   // k group
  const float cm = cmp[0];
  const float* __restrict__ Xp = (m & 1) ? XFs : XFc;
  const float* __restrict__ Dm = D + (size_t)m * (NO * NI);
  const int i0 = ihalf * 128 + w * 32;   // multiple of 32

  f32x4 acc[2][8];
#pragma unroll
  for (int a = 0; a < 2; a++)
#pragma unroll
    for (int b = 0; b < 8; b++) acc[a][b] = (f32x4)0.f;

  for (int kk = 0; kk < NI; kk += 32) {
    const int kb = kk + lg * 8;
    short8 af[2];
#pragma unroll
    for (int rf = 0; rf < 2; rf++) {
      const float* ap = Xp + (size_t)(i0 + rf * 16 + lr) * NI + kb;
      float4 x0 = *(const float4*)ap;
      float4 x1 = *(const float4*)(ap + 4);
      af[rf] = cvt8(x0, x1, cm);
    }
    short8 bf[8];
#pragma unroll
    for (int cf = 0; cf < 8; cf++) {
      const float* bp = Dm + (size_t)(cf * 16 + lr) * NI + kb;
      float4 x0 = *(const float4*)bp;
      float4 x1 = *(const float4*)(bp + 4);
      bf[cf] = cvt8(x0, x1, 1.0f);
    }
#pragma unroll
    for (int rf = 0; rf < 2; rf++)
#pragma unroll
      for (int cf = 0; cf < 8; cf++)
        acc[rf][cf] = __builtin_amdgcn_mfma_f32_16x16x32_bf16(
            af[rf], bf[cf], acc[rf][cf], 0, 0, 0);
  }

  // acc C/D: o = cf*16 + lr, i = i0 + rf*16 + lg*4 + reg.
  // Consumer layout: lane L of (t,cf) holds E[i = t*32 + (L>>4)*8 + j][o =
  // cf*16 + (L&15)], j=0..7. Our 4 regs are half of one 8-run:
  //   t = (i0 + rf*16) >> 5, L = ((2*rf + (lg>>1)) & 3)*16 + lr, j0 = (lg&1)*4
  unsigned short* Bm = Bpack + (size_t)m * BPACK_M;
#pragma unroll
  for (int rf = 0; rf < 2; rf++) {
    const int t = (i0 + rf * 16) >> 5;
    const int L = ((2 * rf + (lg >> 1)) & 3) * 16 + lr;
#pragma unroll
    for (int cf = 0; cf < 8; cf++) {
      ushort4 pk;
      pk.x = f2bf(acc[rf][cf][0]);
      pk.y = f2bf(acc[rf][cf][1]);
      pk.z = f2bf(acc[rf][cf][2]);
      pk.w = f2bf(acc[rf][cf][3]);
      *(ushort4*)(Bm + (size_t)(t * 8 + cf) * 512 + L * 8 + (lg & 1) * 4) = pk;
    }
  }
}

// ---------------- Kernel 2: main GEMM, 32-row blocks, 5 blocks/CU ----------
// grid: (NM fast, NBATCH/32). 256 threads = 4 waves; block = 32(b) x 128(o)
// at one m. Wave w: rows (w>>1)*16 .. +15, o-half (w&1)*64 (cf (w&1)*4..+3).
// LDS As: [32 rows][1024B]. Physical 32B-unit p of row r holds logical unit
// (p ^ (r&7)) — realized by pre-swizzling the glds SOURCE (dest linear),
// undone by the same XOR on the ds_read side (rule #21).
#define LOADB4(BUF, t)                                                  \
  _Pragma("unroll")                                                     \
  for (int j = 0; j < 4; j++)                                           \
    BUF[j] = *(const short8*)(Bm + ((t) * 8 + cfbase + j) * 512 + lane * 8);

#define SB __builtin_amdgcn_sched_barrier(0)

__global__ __launch_bounds__(256, 5) void fdlt_main(
    const float* __restrict__ psiHat,
    const unsigned short* __restrict__ Bpack,
    float* __restrict__ out)
{
  __shared__ float As_f[32 * 256];   // 32 KB -> 5 blocks/CU
  const int m = blockIdx.x;
  const int tid = threadIdx.x;
  const int lane = tid & 63;
  const int w = tid >> 6;
  const int b0 = blockIdx.y * 32;
  const int lr = lane & 15;
  const int lg = lane >> 4;
  const int cfbase = (w & 1) * 4;
  char* As = (char*)As_f;

  // ---- stage: 8 glds per wave, each = one full 1KB contiguous row ----
  // lane covers 16B-unit u; logical 32B-unit = u>>1, piece = u&1;
  // source float offset = (((u>>1) ^ (r&7)) << 3) + ((u&1) << 2).
#pragma unroll
  for (int s = 0; s < 8; s++) {
    const int r = s * 4 + w;
    const int fofs = ((((lane >> 1) ^ (r & 7)) << 3) + ((lane & 1) << 2));
    const float* src = psiHat + ((size_t)(b0 + r) * NM + m) * NI + fofs;
    __builtin_amdgcn_global_load_lds(GLB(src), LDS(As + r * 1024), 16, 0, 0);
  }

  f32x4 acc[4];
#pragma unroll
  for (int b = 0; b < 4; b++) acc[b] = (f32x4)0.f;

  const unsigned short* __restrict__ Bm = Bpack + (size_t)m * BPACK_M;

  // B[0] prefetch overlaps the stage drain (independent of LDS)
  short8 bf0[4], bf1[4];
  LOADB4(bf0, 0);
  SB;

  __syncthreads();   // vmcnt(0) drain + barrier: As ready

  const int arow = (w >> 1) * 16 + lr;   // this lane's A row (16 % 8 == 0)
  const char* Arow = As + arow * 1024;
  const int rsw = lr & 7;                // == arow & 7

#pragma unroll
  for (int t = 0; t < 8; t++) {
    // prefetch next B while computing this step
    if (t < 7) { LOADB4(((t & 1) ? bf0 : bf1), t + 1); SB; }
    // A-frag from LDS: logical 32B-unit L = t*4 + lg, phys = L ^ rsw
    const int p = ((t * 4 + lg) ^ rsw) << 5;
    float4 x0 = *(const float4*)(Arow + p);
    float4 x1 = *(const float4*)(Arow + p + 16);
    short8 af = cvt8(x0, x1, 1.0f);
    const short8* bf = (t & 1) ? bf1 : bf0;
#pragma unroll
    for (int j = 0; j < 4; j++)
      acc[j] = __builtin_amdgcn_mfma_f32_16x16x32_bf16(
          af, bf[j], acc[j], 0, 0, 0);
  }

  // out[b][m][o]; C/D: col = lane&15 (= o-in-frag), row = lg*4+reg (= b off)
#pragma unroll
  for (int j = 0; j < 4; j++) {
    const int o = (cfbase + j) * 16 + lr;
#pragma unroll
    for (int r = 0; r < 4; r++) {
      const int b = b0 + (w >> 1) * 16 + lg * 4 + r;
      out[((size_t)b * NM + m) * NO + o] = acc[j][r];
    }
  }
}

extern "C" void kernel_launch(void* const* d_in, const int* in_sizes, int n_in,
                              void* d_out, int out_size, void* d_ws, size_t ws_size,
                              hipStream_t stream) {
  const float* psiHat = (const float*)d_in[0];
  const float* cm     = (const float*)d_in[1];
  const float* XFc    = (const float*)d_in[2];
  const float* XFs    = (const float*)d_in[3];
  const float* D      = (const float*)d_in[4];
  float* out = (float*)d_out;
  unsigned short* Bpack = (unsigned short*)d_ws;  // 128*32768*2 = 8.39 MB

  e_kernel<<<256, 256, 0, stream>>>(XFc, XFs, D, cm, Bpack);
  fdlt_main<<<dim3(NM, NBATCH / 32), 256, 0, stream>>>(psiHat, Bpack, out);
}

// Round 11
// 105.222 us; speedup vs baseline: 1.2627x; 1.2627x over previous
//
#include <hip/hip_runtime.h>

// FDLT: out[b,m,o] = sum_i psiHat[b,m,i] * E[m][i][o]
//   E[m] = cm * X_parity(m) @ D[m]^T   (X = XFc even m, XFs odd m)
// BATCH=2048, B=128 (m), N=256 (i), O=128 (o)
//
// Kernel 1: e_kernel -> Bpack[m][t][cf][lane]·16B (MFMA fragment-packed).
// Kernel 2 (r11 = r10 race-fixed): never-drain slab pipeline. Block = one m
//   x 512 b-rows as 16 slabs of 32; LDS 2x32KB dbuf; B (Bpack[m]) hoisted
//   once into 128 VGPR (compute phase = zero VMEM). Race fix vs r10:
//   counted vmcnt comes BEFORE a barrier (vmcnt is per-wave; LDS rows are
//   produced cross-wave). Per slab: barrier1 (readers done) -> STAGE(s+2)
//   -> vmcnt(24) (retires own stage(s+1); stage(s+2)+stores stay in flight)
//   -> barrier2 (stage(s+1) globally visible) -> compute(s+1).

typedef __attribute__((ext_vector_type(8))) short short8;
typedef __attribute__((ext_vector_type(4))) float f32x4;

#define NBATCH 2048
#define NM 128
#define NI 256   // K dim (i / j)
#define NO 128   // output o dim
// Bpack per m: 8 t-steps x 8 cf x 64 lanes x 8 bf16 = 32768 shorts (64 KB)
#define BPACK_M 32768

#define NSLAB 16
#define SLABROWS 32
#define LDSBUF 32768   // bytes per slab buffer (32 rows x 1024 B)

#define GLB(p) ((const __attribute__((address_space(1))) void*)(p))
#define LDS(p) ((__attribute__((address_space(3))) void*)(p))

__device__ __forceinline__ unsigned short f2bf(float f) {
  // round-to-nearest-even fp32 -> bf16
  unsigned int u = __builtin_bit_cast(unsigned int, f);
  u += 0x7FFFu + ((u >> 16) & 1u);
  return (unsigned short)(u >> 16);
}

__device__ __forceinline__ short8 cvt8(float4 a, float4 b, float s) {
  short8 v;
  v[0] = (short)f2bf(s * a.x); v[1] = (short)f2bf(s * a.y);
  v[2] = (short)f2bf(s * a.z); v[3] = (short)f2bf(s * a.w);
  v[4] = (short)f2bf(s * b.x); v[5] = (short)f2bf(s * b.y);
  v[6] = (short)f2bf(s * b.z); v[7] = (short)f2bf(s * b.w);
  return v;
}

// ---------------- Kernel 1: E precompute -> fragment-packed Bpack ----------
__global__ __launch_bounds__(256) void e_kernel(
    const float* __restrict__ XFc, const float* __restrict__ XFs,
    const float* __restrict__ D, const float* __restrict__ cmp,
    unsigned short* __restrict__ Bpack)
{
  const int m = blockIdx.x >> 1;
  const int ihalf = blockIdx.x & 1;
  const int tid = threadIdx.x;
  const int lane = tid & 63;
  const int w = tid >> 6;
  const int lr = lane & 15;   // frag row (A) / col (B)
  const int lg = lane >> 4;   // k group
  const float cm = cmp[0];
  const float* __restrict__ Xp = (m & 1) ? XFs : XFc;
  const float* __restrict__ Dm = D + (size_t)m * (NO * NI);
  const int i0 = ihalf * 128 + w * 32;   // multiple of 32

  f32x4 acc[2][8];
#pragma unroll
  for (int a = 0; a < 2; a++)
#pragma unroll
    for (int b = 0; b < 8; b++) acc[a][b] = (f32x4)0.f;

  for (int kk = 0; kk < NI; kk += 32) {
    const int kb = kk + lg * 8;
    short8 af[2];
#pragma unroll
    for (int rf = 0; rf < 2; rf++) {
      const float* ap = Xp + (size_t)(i0 + rf * 16 + lr) * NI + kb;
      float4 x0 = *(const float4*)ap;
      float4 x1 = *(const float4*)(ap + 4);
      af[rf] = cvt8(x0, x1, cm);
    }
    short8 bf[8];
#pragma unroll
    for (int cf = 0; cf < 8; cf++) {
      const float* bp = Dm + (size_t)(cf * 16 + lr) * NI + kb;
      float4 x0 = *(const float4*)bp;
      float4 x1 = *(const float4*)(bp + 4);
      bf[cf] = cvt8(x0, x1, 1.0f);
    }
#pragma unroll
    for (int rf = 0; rf < 2; rf++)
#pragma unroll
      for (int cf = 0; cf < 8; cf++)
        acc[rf][cf] = __builtin_amdgcn_mfma_f32_16x16x32_bf16(
            af[rf], bf[cf], acc[rf][cf], 0, 0, 0);
  }

  // acc C/D: o = cf*16 + lr, i = i0 + rf*16 + lg*4 + reg.
  // Consumer layout: lane L of (t,cf) holds E[i = t*32 + (L>>4)*8 + j][o =
  // cf*16 + (L&15)], j=0..7. Our 4 regs are half of one 8-run:
  //   t = (i0 + rf*16) >> 5, L = ((2*rf + (lg>>1)) & 3)*16 + lr, j0 = (lg&1)*4
  unsigned short* Bm = Bpack + (size_t)m * BPACK_M;
#pragma unroll
  for (int rf = 0; rf < 2; rf++) {
    const int t = (i0 + rf * 16) >> 5;
    const int L = ((2 * rf + (lg >> 1)) & 3) * 16 + lr;
#pragma unroll
    for (int cf = 0; cf < 8; cf++) {
      ushort4 pk;
      pk.x = f2bf(acc[rf][cf][0]);
      pk.y = f2bf(acc[rf][cf][1]);
      pk.z = f2bf(acc[rf][cf][2]);
      pk.w = f2bf(acc[rf][cf][3]);
      *(ushort4*)(Bm + (size_t)(t * 8 + cf) * 512 + L * 8 + (lg & 1) * 4) = pk;
    }
  }
}

// ---------------- Kernel 2: main GEMM, never-drain slab pipeline -----------
// grid: (NM fast, NBATCH/(NSLAB*SLABROWS)) = (128, 4). 256 threads = 4 waves.
// Block: one m, rows bbase..+511 as 16 slabs of 32. Wave w computes rows
// (w>>1)*16..+15 of each slab, o-half (w&1) (cf = (w&1)*4..+3).
// LDS: [2][32 rows][1024 B], 32B-unit XOR swizzle (unit ^= row&7) applied to
// glds SOURCE (dest linear) and undone on ds_read (rule #21; r8/r9-verified).
#define SB __builtin_amdgcn_sched_barrier(0)

__global__ __launch_bounds__(256, 2) void fdlt_main(
    const float* __restrict__ psiHat,
    const unsigned short* __restrict__ Bpack,
    float* __restrict__ out)
{
  __shared__ float As_f[2 * SLABROWS * 256];   // 64 KB -> 2 blocks/CU
  const int m = blockIdx.x;
  const int tid = threadIdx.x;
  const int lane = tid & 63;
  const int w = tid >> 6;
  const int bbase = blockIdx.y * (NSLAB * SLABROWS);
  const int lr = lane & 15;
  const int lg = lane >> 4;
  const int cfbase = (w & 1) * 4;
  char* As = (char*)As_f;

  const unsigned short* __restrict__ Bm = Bpack + (size_t)m * BPACK_M;

  // ---- B resident for the whole block: 32 x short8 = 128 VGPR ----
  short8 ball[8][4];
#pragma unroll
  for (int t = 0; t < 8; t++)
#pragma unroll
    for (int j = 0; j < 4; j++)
      ball[t][j] =
          *(const short8*)(Bm + (size_t)(t * 8 + cfbase + j) * 512 + lane * 8);

  // ---- staging: 8 glds, each one full 1KB contiguous psiHat row ----
  // lane covers 16B-unit u; logical 32B-unit = u>>1, piece = u&1;
  // source float offset = (((u>>1) ^ (r&7)) << 3) + ((u&1) << 2).
  auto STAGE = [&](int buf, int s) {
#pragma unroll
    for (int j = 0; j < 8; j++) {
      const int r = j * 4 + w;
      const int fofs = ((((lane >> 1) ^ (r & 7)) << 3) + ((lane & 1) << 2));
      const float* src =
          psiHat + ((size_t)(bbase + s * SLABROWS + r) * NM + m) * NI + fofs;
      __builtin_amdgcn_global_load_lds(GLB(src), LDS(As + buf * LDSBUF + r * 1024),
                                       16, 0, 0);
    }
  };

  const int arow = (w >> 1) * 16 + lr;   // row-in-slab this lane reads
  const int rsw = lr & 7;                // == arow & 7
  f32x4 acc[4];

  STAGE(0, 0);
  STAGE(1, 1);
  // retire own B-preload(32) + own stage(0)(8); keep stage(1)(8) in flight
  asm volatile("s_waitcnt vmcnt(8)" ::: "memory");
  SB;
  __builtin_amdgcn_s_barrier();   // all waves' stage(0) now visible
  SB;

  for (int s = 0; s < NSLAB; s++) {
    // ---- compute slab s from buf (s&1); zero VMEM in this phase ----
    const char* Arow = As + (s & 1) * LDSBUF + arow * 1024;
#pragma unroll
    for (int j = 0; j < 4; j++) acc[j] = (f32x4)0.f;
#pragma unroll
    for (int t = 0; t < 8; t++) {
      const int p = ((t * 4 + lg) ^ rsw) << 5;
      float4 x0 = *(const float4*)(Arow + p);
      float4 x1 = *(const float4*)(Arow + p + 16);
      short8 af = cvt8(x0, x1, 1.0f);
#pragma unroll
      for (int j = 0; j < 4; j++)
        acc[j] = __builtin_amdgcn_mfma_f32_16x16x32_bf16(
            af, ball[t][j], acc[j], 0, 0, 0);
    }

    // ---- store slab s: 16 dwords/lane (fire-and-forget) ----
#pragma unroll
    for (int j = 0; j < 4; j++) {
      const int o = (cfbase + j) * 16 + lr;
#pragma unroll
      for (int r = 0; r < 4; r++) {
        const int b = bbase + s * SLABROWS + (w >> 1) * 16 + lg * 4 + r;
        out[((size_t)b * NM + m) * NO + o] = acc[j][r];
      }
    }

    // ---- pipeline maintenance: vmcnt BEFORE barrier (per-wave counters,
    //      cross-wave LDS production — the r10 race fix) ----
    if (s + 1 < NSLAB) {
      __builtin_amdgcn_s_barrier();       // all readers done with buf(s&1)
      if (s + 2 < NSLAB) {
        STAGE((s + 2) & 1, s + 2);        // overwrite buf(s&1)
        // FIFO retire: leaves youngest 24 = stores(s)[16] + stage(s+2)[8];
        // everything older (incl. own stage(s+1)) retired.
        asm volatile("s_waitcnt vmcnt(24)" ::: "memory");
      } else {
        // leaves youngest 16 = stores(s); own stage(s+1) retired.
        asm volatile("s_waitcnt vmcnt(16)" ::: "memory");
      }
      SB;
      __builtin_amdgcn_s_barrier();       // stage(s+1) visible to all waves
      SB;
    }
  }
}

extern "C" void kernel_launch(void* const* d_in, const int* in_sizes, int n_in,
                              void* d_out, int out_size, void* d_ws, size_t ws_size,
                              hipStream_t stream) {
  const float* psiHat = (const float*)d_in[0];
  const float* cm     = (const float*)d_in[1];
  const float* XFc    = (const float*)d_in[2];
  const float* XFs    = (const float*)d_in[3];
  const float* D      = (const float*)d_in[4];
  float* out = (float*)d_out;
  unsigned short* Bpack = (unsigned short*)d_ws;  // 128*32768*2 = 8.39 MB

  e_kernel<<<256, 256, 0, stream>>>(XFc, XFs, D, cm, Bpack);
  fdlt_main<<<dim3(NM, NBATCH / (NSLAB * SLABROWS)), 256, 0, stream>>>(
      psiHat, Bpack, out);
}